// Round 1
// baseline (1268.982 us; speedup 1.0000x reference)
//
#include <hip/hip_runtime.h>
#include <math.h>

// Problem dims
constexpr int Bb  = 4;
constexpr int Ls  = 2048;
constexpr int DM  = 256;   // d_model
constexpr int DI  = 512;   // d_inner
constexpr int DSt = 16;    // d_state
constexpr int DCv = 4;     // d_conv
constexpr int DRk = 16;    // dt_rank
constexpr int NL  = 4;
constexpr int DIN = 64;
constexpr int M   = Bb * Ls;   // 8192 tokens

// Chunked scan config
#define NCH 64   // chunks
#define CLN 32   // chunk length (NCH*CLN == Ls)

__device__ __forceinline__ float silu_f(float x) {
  return x / (1.f + __expf(-x));
}
__device__ __forceinline__ float softplus_f(float x) {
  // stable: max(x,0) + log1p(exp(-|x|))  == logaddexp(x, 0)
  return fmaxf(x, 0.f) + log1pf(__expf(-fabsf(x)));
}

// ---------------------------------------------------------------------------
// Weight transpose: src is (nm, N, K) row-major; dst is (nm, K, N).
// ---------------------------------------------------------------------------
__global__ __launch_bounds__(256) void transpose_w(
    const float* __restrict__ src, float* __restrict__ dst,
    int nm, int N, int K) {
  int idx = blockIdx.x * 256 + threadIdx.x;
  int total = nm * N * K;
  if (idx >= total) return;
  int m = idx / (N * K);
  int r = idx - m * (N * K);
  int n = r / K;
  int k = r - n * K;
  dst[(size_t)m * N * K + (size_t)k * N + n] = src[idx];
}

// ---------------------------------------------------------------------------
// Generic token-tiled matmul: C[M,N] = A[M,K(lda)] * Wt[K,N] (+bias)
// Block = 256 threads, TM tokens per block, PT = N/256 columns per thread.
// MODE 0: plain (+bias if non-null). MODE 1: softplus(acc + bias).
// ---------------------------------------------------------------------------
template <int K, int N, int TM, int PT, int MODE>
__global__ __launch_bounds__(256) void matmul_tm(
    const float* __restrict__ A, int lda,
    const float* __restrict__ Wt, const float* __restrict__ bias,
    float* __restrict__ C) {
  __shared__ float As[TM][K];
  const int m0 = blockIdx.x * TM;
  const int t = threadIdx.x;

  for (int i = t; i < TM * K; i += 256) {
    int mm = i / K, kk = i % K;
    As[mm][kk] = A[(size_t)(m0 + mm) * lda + kk];
  }
  __syncthreads();

  float acc[TM][PT];
#pragma unroll
  for (int mm = 0; mm < TM; mm++)
#pragma unroll
    for (int p = 0; p < PT; p++) acc[mm][p] = 0.f;

  for (int k = 0; k < K; k++) {
    float w[PT];
#pragma unroll
    for (int p = 0; p < PT; p++) w[p] = Wt[(size_t)k * N + p * 256 + t];
#pragma unroll
    for (int mm = 0; mm < TM; mm++) {
      float a = As[mm][k];
#pragma unroll
      for (int p = 0; p < PT; p++) acc[mm][p] = fmaf(a, w[p], acc[mm][p]);
    }
  }

#pragma unroll
  for (int mm = 0; mm < TM; mm++) {
#pragma unroll
    for (int p = 0; p < PT; p++) {
      int n = p * 256 + t;
      float v = acc[mm][p];
      if (bias) v += bias[n];
      if (MODE == 1) v = softplus_f(v);
      C[(size_t)(m0 + mm) * N + n] = v;
    }
  }
}

// ---------------------------------------------------------------------------
// Causal depthwise conv (k=4) + SiLU. u lives in xz[:, 0:512] (row stride 1024)
// ---------------------------------------------------------------------------
__global__ __launch_bounds__(256) void conv_silu_kernel(
    const float* __restrict__ xz, const float* __restrict__ convw_l,
    const float* __restrict__ convb_l, float* __restrict__ uc) {
  int idx = blockIdx.x * 256 + threadIdx.x;  // (b, l, d), d fast
  int d = idx & (DI - 1);
  int l = (idx >> 9) & (Ls - 1);
  int b = idx >> 20;
  float acc = convb_l[d];
#pragma unroll
  for (int k = 0; k < DCv; k++) {
    int ls = l + k - (DCv - 1);
    if (ls >= 0) {
      acc = fmaf(xz[((size_t)(b * Ls + ls)) * (2 * DI) + d], convw_l[d * DCv + k], acc);
    }
  }
  uc[(size_t)idx] = silu_f(acc);
}

// ---------------------------------------------------------------------------
// dbc = uc(8192x512) @ xpw_t (512x48). Block = 4 tokens x 64 slots (48 active).
// ---------------------------------------------------------------------------
__global__ __launch_bounds__(256) void xpw_matmul_kernel(
    const float* __restrict__ uc, const float* __restrict__ Wt,
    float* __restrict__ dbc) {
  __shared__ float As[4][DI];
  int m0 = blockIdx.x * 4;
  int t = threadIdx.x;
  for (int i = t; i < 4 * DI; i += 256) {
    int mm = i >> 9, kk = i & (DI - 1);
    As[mm][kk] = uc[(size_t)(m0 + mm) * DI + kk];
  }
  __syncthreads();
  int n = t & 63, mm = t >> 6;
  if (n < 48) {
    float acc = 0.f;
    for (int k = 0; k < DI; k++) acc = fmaf(As[mm][k], Wt[k * 48 + n], acc);
    dbc[(size_t)(m0 + mm) * 48 + n] = acc;
  }
}

// ---------------------------------------------------------------------------
// Scan pass 1: per (b, chunk, d) compute transition product P[s] and local
// end-state hloc[s] (starting from h=0). Layout (b, c, d, s), s innermost.
// ---------------------------------------------------------------------------
__global__ __launch_bounds__(256) void scan1_kernel(
    const float* __restrict__ delta, const float* __restrict__ uc,
    const float* __restrict__ dbc, const float* __restrict__ a_log_l,
    float* __restrict__ P, float* __restrict__ hloc) {
  int idx = blockIdx.x * 256 + threadIdx.x;  // (b*NCH + c)*DI + d
  int d = idx & (DI - 1);
  int c = (idx >> 9) & (NCH - 1);
  int b = idx >> 15;  // 9 + 6
  float Aa[DSt];
#pragma unroll
  for (int s = 0; s < DSt; s++) Aa[s] = -__expf(a_log_l[d * DSt + s]);
  float p[DSt], h[DSt];
#pragma unroll
  for (int s = 0; s < DSt; s++) { p[s] = 1.f; h[s] = 0.f; }

  int base_l = b * Ls + c * CLN;
  for (int tt = 0; tt < CLN; tt++) {
    size_t row = (size_t)(base_l + tt);
    float dlt = delta[row * DI + d];
    float uu = uc[row * DI + d];
    float du = dlt * uu;
    const float* Bp = dbc + row * 48 + DRk;
#pragma unroll
    for (int s = 0; s < DSt; s++) {
      float dA = __expf(dlt * Aa[s]);
      p[s] *= dA;
      h[s] = fmaf(dA, h[s], du * Bp[s]);
    }
  }
  size_t o = (size_t)idx * DSt;
#pragma unroll
  for (int s = 0; s < DSt; s++) { P[o + s] = p[s]; hloc[o + s] = h[s]; }
}

// ---------------------------------------------------------------------------
// Scan pass 2: stitch chunk boundary states. Thread per (b, d, s).
// ---------------------------------------------------------------------------
__global__ __launch_bounds__(256) void scan2_kernel(
    const float* __restrict__ P, const float* __restrict__ hloc,
    float* __restrict__ h0) {
  int idx = blockIdx.x * 256 + threadIdx.x;  // b*(DI*DSt) + ds
  int b = idx >> 13;                         // DI*DSt = 8192
  int ds = idx & 8191;
  float h = 0.f;
  for (int c = 0; c < NCH; c++) {
    size_t o = ((size_t)(b * NCH + c)) * (DI * DSt) + ds;
    h0[o] = h;
    h = fmaf(P[o], h, hloc[o]);
  }
}

// ---------------------------------------------------------------------------
// Scan pass 3: replay each chunk from h0, emit y (overwrites delta buffer).
// ---------------------------------------------------------------------------
__global__ __launch_bounds__(256) void scan3_kernel(
    float* __restrict__ delta_y, const float* __restrict__ uc,
    const float* __restrict__ dbc, const float* __restrict__ a_log_l,
    const float* __restrict__ dparam_l, const float* __restrict__ h0) {
  int idx = blockIdx.x * 256 + threadIdx.x;
  int d = idx & (DI - 1);
  int c = (idx >> 9) & (NCH - 1);
  int b = idx >> 15;
  float Aa[DSt];
#pragma unroll
  for (int s = 0; s < DSt; s++) Aa[s] = -__expf(a_log_l[d * DSt + s]);
  float h[DSt];
  size_t o = (size_t)idx * DSt;
#pragma unroll
  for (int s = 0; s < DSt; s++) h[s] = h0[o + s];
  float Dp = dparam_l[d];

  int base_l = b * Ls + c * CLN;
  for (int tt = 0; tt < CLN; tt++) {
    size_t row = (size_t)(base_l + tt);
    float dlt = delta_y[row * DI + d];
    float uu = uc[row * DI + d];
    float du = dlt * uu;
    const float* Bp = dbc + row * 48 + DRk;
    const float* Cp = dbc + row * 48 + DRk + DSt;
    float y = 0.f;
#pragma unroll
    for (int s = 0; s < DSt; s++) {
      float dA = __expf(dlt * Aa[s]);
      h[s] = fmaf(dA, h[s], du * Bp[s]);
      y = fmaf(h[s], Cp[s], y);
    }
    y = fmaf(uu, Dp, y);
    delta_y[row * DI + d] = y;
  }
}

// ---------------------------------------------------------------------------
// Fused: ygated = y * silu(z); out = ygated @ outw_t (512x256); +residual;
// LayerNorm over 256. Block = 256 threads (one per output col), TM=8 tokens.
// ---------------------------------------------------------------------------
__global__ __launch_bounds__(256) void gate_out_ln_kernel(
    const float* __restrict__ ybuf, const float* __restrict__ xz,
    const float* __restrict__ Wt, const float* __restrict__ res,
    const float* __restrict__ lnw_l, const float* __restrict__ lnb_l,
    float* __restrict__ hout) {
  const int TM = 8;
  __shared__ float As[TM][DI];
  __shared__ float red[8];
  int m0 = blockIdx.x * TM;
  int t = threadIdx.x;

  for (int i = t; i < TM * DI; i += 256) {
    int mm = i >> 9, kk = i & (DI - 1);
    float y = ybuf[(size_t)(m0 + mm) * DI + kk];
    float z = xz[(size_t)(m0 + mm) * (2 * DI) + DI + kk];
    As[mm][kk] = y * silu_f(z);
  }
  __syncthreads();

  float acc[TM];
#pragma unroll
  for (int mm = 0; mm < TM; mm++) acc[mm] = 0.f;
  for (int k = 0; k < DI; k++) {
    float w = Wt[k * DM + t];
#pragma unroll
    for (int mm = 0; mm < TM; mm++) acc[mm] = fmaf(As[mm][k], w, acc[mm]);
  }

  for (int mm = 0; mm < TM; mm++) {
    float v = acc[mm] + res[(size_t)(m0 + mm) * DM + t];
    float s1 = v, s2 = v * v;
#pragma unroll
    for (int off = 32; off > 0; off >>= 1) {
      s1 += __shfl_down(s1, off, 64);
      s2 += __shfl_down(s2, off, 64);
    }
    __syncthreads();
    if ((t & 63) == 0) { red[t >> 6] = s1; red[4 + (t >> 6)] = s2; }
    __syncthreads();
    float mu = (red[0] + red[1] + red[2] + red[3]) * (1.f / 256.f);
    float msq = (red[4] + red[5] + red[6] + red[7]) * (1.f / 256.f);
    float inv = rsqrtf(msq - mu * mu + 1e-5f);
    hout[(size_t)(m0 + mm) * DM + t] = (v - mu) * inv * lnw_l[t] + lnb_l[t];
  }
}

// ---------------------------------------------------------------------------
extern "C" void kernel_launch(void* const* d_in, const int* in_sizes, int n_in,
                              void* d_out, int out_size, void* d_ws,
                              size_t ws_size, hipStream_t stream) {
  const float* x      = (const float*)d_in[0];
  const float* ipw    = (const float*)d_in[1];
  const float* ipb    = (const float*)d_in[2];
  const float* opw    = (const float*)d_in[3];
  const float* opb    = (const float*)d_in[4];
  const float* inw    = (const float*)d_in[5];
  const float* convw  = (const float*)d_in[6];
  const float* convb  = (const float*)d_in[7];
  const float* xpw    = (const float*)d_in[8];
  const float* dtw    = (const float*)d_in[9];
  const float* dtb    = (const float*)d_in[10];
  const float* a_log  = (const float*)d_in[11];
  const float* dparam = (const float*)d_in[12];
  const float* outw   = (const float*)d_in[13];
  const float* lnw    = (const float*)d_in[14];
  const float* lnb    = (const float*)d_in[15];
  float* out = (float*)d_out;

  float* ws = (float*)d_ws;
  size_t o = 0;
  float* hA   = ws + o; o += (size_t)M * DM;        // 2,097,152
  float* hB   = ws + o; o += (size_t)M * DM;
  float* xz   = ws + o; o += (size_t)M * 2 * DI;    // 8,388,608
  float* uc   = ws + o; o += (size_t)M * DI;
  float* dbc  = ws + o; o += (size_t)M * 48;
  float* dlt  = ws + o; o += (size_t)M * DI;        // also holds y after scan3
  size_t scan_sz = (size_t)Bb * NCH * DI * DSt;     // 2,097,152
  float* Pb   = ws + o; o += scan_sz;
  float* hlb  = ws + o; o += scan_sz;
  float* h0b  = ws + o; o += scan_sz;
  float* ipw_t = ws + o; o += (size_t)DIN * DM;
  float* inw_t = ws + o; o += (size_t)NL * DM * 2 * DI;
  float* xpw_t = ws + o; o += (size_t)NL * 48 * DI;
  float* dtw_t = ws + o; o += (size_t)NL * DRk * DI;
  float* outw_t = ws + o; o += (size_t)NL * DI * DM;
  float* opw_t = ws + o; o += (size_t)DM * DM;
  (void)ws_size; (void)in_sizes; (void)n_in; (void)out_size;

  auto T = [&](const float* s, float* dst, int nm, int N, int K) {
    int total = nm * N * K;
    transpose_w<<<dim3((total + 255) / 256), dim3(256), 0, stream>>>(s, dst, nm, N, K);
  };
  T(ipw, ipw_t, 1, DM, DIN);
  T(inw, inw_t, NL, 2 * DI, DM);
  T(xpw, xpw_t, NL, 48, DI);
  T(dtw, dtw_t, NL, DI, DRk);
  T(outw, outw_t, NL, DM, DI);
  T(opw, opw_t, 1, DM, DM);

  // input projection: x(8192x64) @ ipw_t(64x256) + b -> hA
  matmul_tm<DIN, DM, 16, 1, 0><<<dim3(M / 16), dim3(256), 0, stream>>>(
      x, DIN, ipw_t, ipb, hA);

  float* hcur = hA;
  float* hnxt = hB;
  for (int l = 0; l < NL; l++) {
    const float* inw_tl  = inw_t + (size_t)l * DM * 2 * DI;
    const float* xpw_tl  = xpw_t + (size_t)l * 48 * DI;
    const float* dtw_tl  = dtw_t + (size_t)l * DRk * DI;
    const float* outw_tl = outw_t + (size_t)l * DI * DM;
    const float* a_log_l = a_log + (size_t)l * DI * DSt;

    // xz = h @ inw^T  (8192 x 1024)
    matmul_tm<DM, 2 * DI, 16, 4, 0><<<dim3(M / 16), dim3(256), 0, stream>>>(
        hcur, DM, inw_tl, nullptr, xz);
    // conv + silu -> uc
    conv_silu_kernel<<<dim3(M * DI / 256), dim3(256), 0, stream>>>(
        xz, convw + (size_t)l * DI * DCv, convb + (size_t)l * DI, uc);
    // dbc = uc @ xpw^T (8192 x 48)
    xpw_matmul_kernel<<<dim3(M / 4), dim3(256), 0, stream>>>(uc, xpw_tl, dbc);
    // delta = softplus(dt @ dtw^T + dtb) (8192 x 512); dt = dbc[:, :16], lda=48
    matmul_tm<DRk, DI, 16, 2, 1><<<dim3(M / 16), dim3(256), 0, stream>>>(
        dbc, 48, dtw_tl, dtb + (size_t)l * DI, dlt);
    // chunked selective scan
    scan1_kernel<<<dim3(Bb * NCH * DI / 256), dim3(256), 0, stream>>>(
        dlt, uc, dbc, a_log_l, Pb, hlb);
    scan2_kernel<<<dim3(Bb * DI * DSt / 256), dim3(256), 0, stream>>>(Pb, hlb, h0b);
    scan3_kernel<<<dim3(Bb * NCH * DI / 256), dim3(256), 0, stream>>>(
        dlt, uc, dbc, a_log_l, dparam + (size_t)l * DI, h0b);
    // gate + out matmul + residual + layernorm -> hnxt
    gate_out_ln_kernel<<<dim3(M / 8), dim3(256), 0, stream>>>(
        dlt, xz, outw_tl, hcur, lnw + (size_t)l * DM, lnb + (size_t)l * DM, hnxt);
    float* tmp = hcur; hcur = hnxt; hnxt = tmp;
  }

  // final projection: hcur(8192x256) @ opw_t(256x256) + b -> out
  matmul_tm<DM, DM, 16, 1, 0><<<dim3(M / 16), dim3(256), 0, stream>>>(
      hcur, DM, opw_t, opb, out);
}

// Round 2
// 909.178 us; speedup vs baseline: 1.3957x; 1.3957x over previous
//
#include <hip/hip_runtime.h>
#include <math.h>

// Problem dims
constexpr int Bb  = 4;
constexpr int Ls  = 2048;
constexpr int DM  = 256;   // d_model
constexpr int DI  = 512;   // d_inner
constexpr int DSt = 16;    // d_state
constexpr int DCv = 4;     // d_conv
constexpr int DRk = 16;    // dt_rank
constexpr int NL  = 4;
constexpr int DIN = 64;
constexpr int M   = Bb * Ls;   // 8192 tokens

// Chunked scan config
#define NCH 64   // chunks
#define CLN 32   // chunk length (NCH*CLN == Ls)

using f32x4  = __attribute__((ext_vector_type(4))) float;
using bf16x8 = __attribute__((ext_vector_type(8))) __bf16;

__device__ __forceinline__ float silu_f(float x) {
  return x / (1.f + __expf(-x));
}
__device__ __forceinline__ float softplus_f(float x) {
  return fmaxf(x, 0.f) + log1pf(__expf(-fabsf(x)));
}
__device__ __forceinline__ unsigned short f2bf(float x) {
  union { float f; unsigned u; } v; v.f = x;
  unsigned r = v.u + 0x7fff + ((v.u >> 16) & 1);  // RNE
  return (unsigned short)(r >> 16);
}

// ---------------------------------------------------------------------------
// Weight transpose (fp32 path): src (nm, N, K) -> dst (nm, K, N).
// ---------------------------------------------------------------------------
__global__ __launch_bounds__(256) void transpose_w(
    const float* __restrict__ src, float* __restrict__ dst,
    int nm, int N, int K) {
  int idx = blockIdx.x * 256 + threadIdx.x;
  int total = nm * N * K;
  if (idx >= total) return;
  int m = idx / (N * K);
  int r = idx - m * (N * K);
  int n = r / K;
  int k = r - n * K;
  dst[(size_t)m * N * K + (size_t)k * N + n] = src[idx];
}

// fp32 -> bf16 elementwise cast (weights)
__global__ __launch_bounds__(256) void cast_bf16(
    const float* __restrict__ src, unsigned short* __restrict__ dst, int n) {
  int idx = blockIdx.x * 256 + threadIdx.x;
  if (idx < n) dst[idx] = f2bf(src[idx]);
}

// ---------------------------------------------------------------------------
// fp32 token-tiled matmul (small K only now): C = A[M,K(lda)] * Wt[K,N] (+bias)
// MODE 0: plain. MODE 1: softplus(acc + bias). Cb: optional bf16 shadow copy.
// ---------------------------------------------------------------------------
template <int K, int N, int TM, int PT, int MODE>
__global__ __launch_bounds__(256) void matmul_tm(
    const float* __restrict__ A, int lda,
    const float* __restrict__ Wt, const float* __restrict__ bias,
    float* __restrict__ C, unsigned short* __restrict__ Cb) {
  __shared__ float As[TM][K];
  const int m0 = blockIdx.x * TM;
  const int t = threadIdx.x;

  for (int i = t; i < TM * K; i += 256) {
    int mm = i / K, kk = i % K;
    As[mm][kk] = A[(size_t)(m0 + mm) * lda + kk];
  }
  __syncthreads();

  float acc[TM][PT];
#pragma unroll
  for (int mm = 0; mm < TM; mm++)
#pragma unroll
    for (int p = 0; p < PT; p++) acc[mm][p] = 0.f;

  for (int k = 0; k < K; k++) {
    float w[PT];
#pragma unroll
    for (int p = 0; p < PT; p++) w[p] = Wt[(size_t)k * N + p * 256 + t];
#pragma unroll
    for (int mm = 0; mm < TM; mm++) {
      float a = As[mm][k];
#pragma unroll
      for (int p = 0; p < PT; p++) acc[mm][p] = fmaf(a, w[p], acc[mm][p]);
    }
  }

#pragma unroll
  for (int mm = 0; mm < TM; mm++) {
#pragma unroll
    for (int p = 0; p < PT; p++) {
      int n = p * 256 + t;
      float v = acc[mm][p];
      if (bias) v += bias[n];
      if (MODE == 1) v = softplus_f(v);
      C[(size_t)(m0 + mm) * N + n] = v;
      if (Cb) Cb[(size_t)(m0 + mm) * N + n] = f2bf(v);
    }
  }
}

// ---------------------------------------------------------------------------
// bf16 MFMA GEMM: C[M,Ntot] = A[M,K]bf16 * W[Ntot,K]bf16 (W row-major = B^T).
// Block 256 = 4 waves (2x2), tile BM x BN, BK=32 (one 16x16x32 mfma K-step).
// MODE 0: plain; 1: +bias (extra[Ntot]); 2: +residual (extra[M,Ntot]).
// ---------------------------------------------------------------------------
template <int K, int Ntot, int BM, int BN, int MODE>
__global__ __launch_bounds__(256) void gemm_bf16(
    const unsigned short* __restrict__ A,
    const unsigned short* __restrict__ W,
    const float* __restrict__ extra,
    float* __restrict__ C) {
  constexpr int BK = 32, LDK = 40;  // +8 pad: breaks LDS bank aliasing
  constexpr int WM = BM / 2, WN = BN / 2, MI = WM / 16, NI = WN / 16;
  __shared__ __align__(16) unsigned short As[BM * LDK];
  __shared__ __align__(16) unsigned short Bs[BN * LDK];
  const int t = threadIdx.x;
  const int m0 = blockIdx.x * BM, n0 = blockIdx.y * BN;
  const int wave = t >> 6, lane = t & 63;
  const int wm = wave & 1, wn = wave >> 1;
  const int lm = lane & 15, quad = lane >> 4;

  f32x4 acc[MI][NI];
#pragma unroll
  for (int i = 0; i < MI; i++)
#pragma unroll
    for (int j = 0; j < NI; j++) acc[i][j] = (f32x4){0.f, 0.f, 0.f, 0.f};

  for (int k0 = 0; k0 < K; k0 += BK) {
    if (k0) __syncthreads();
    // stage A tile [BM][32] as 16B chunks
    for (int ci = t; ci < BM * 4; ci += 256) {
      int row = ci >> 2, c8 = ci & 3;
      uint4 v = *(const uint4*)(A + (size_t)(m0 + row) * K + k0 + c8 * 8);
      *(uint4*)&As[row * LDK + c8 * 8] = v;
    }
    // stage W tile [BN][32]
    for (int ci = t; ci < BN * 4; ci += 256) {
      int row = ci >> 2, c8 = ci & 3;
      uint4 v = *(const uint4*)(W + (size_t)(n0 + row) * K + k0 + c8 * 8);
      *(uint4*)&Bs[row * LDK + c8 * 8] = v;
    }
    __syncthreads();

    bf16x8 af[MI], bfr[NI];
#pragma unroll
    for (int i = 0; i < MI; i++)
      af[i] = *(const bf16x8*)&As[(wm * WM + i * 16 + lm) * LDK + quad * 8];
#pragma unroll
    for (int j = 0; j < NI; j++)
      bfr[j] = *(const bf16x8*)&Bs[(wn * WN + j * 16 + lm) * LDK + quad * 8];
#pragma unroll
    for (int i = 0; i < MI; i++)
#pragma unroll
      for (int j = 0; j < NI; j++)
        acc[i][j] = __builtin_amdgcn_mfma_f32_16x16x32_bf16(
            af[i], bfr[j], acc[i][j], 0, 0, 0);
  }

  // epilogue: C/D layout col=lane&15, row=quad*4+reg
#pragma unroll
  for (int i = 0; i < MI; i++)
#pragma unroll
    for (int j = 0; j < NI; j++)
#pragma unroll
      for (int r = 0; r < 4; r++) {
        int gr = m0 + wm * WM + i * 16 + quad * 4 + r;
        int gc = n0 + wn * WN + j * 16 + lm;
        float v = acc[i][j][r];
        if constexpr (MODE == 1) v += extra[gc];
        if constexpr (MODE == 2) v += extra[(size_t)gr * Ntot + gc];
        C[(size_t)gr * Ntot + gc] = v;
      }
}

// ---------------------------------------------------------------------------
// Causal depthwise conv (k=4) + SiLU. u lives in xz[:, 0:512] (row stride 1024)
// ---------------------------------------------------------------------------
__global__ __launch_bounds__(256) void conv_silu_kernel(
    const float* __restrict__ xz, const float* __restrict__ convw_l,
    const float* __restrict__ convb_l, float* __restrict__ uc) {
  int idx = blockIdx.x * 256 + threadIdx.x;  // (b, l, d), d fast
  int d = idx & (DI - 1);
  int l = (idx >> 9) & (Ls - 1);
  int b = idx >> 20;
  float acc = convb_l[d];
#pragma unroll
  for (int k = 0; k < DCv; k++) {
    int ls = l + k - (DCv - 1);
    if (ls >= 0) {
      acc = fmaf(xz[((size_t)(b * Ls + ls)) * (2 * DI) + d], convw_l[d * DCv + k], acc);
    }
  }
  uc[(size_t)idx] = silu_f(acc);
}

// ---------------------------------------------------------------------------
// dbc = uc(8192x512) @ xpw_t (512x48). Block = 4 tokens x 64 slots (48 active).
// ---------------------------------------------------------------------------
__global__ __launch_bounds__(256) void xpw_matmul_kernel(
    const float* __restrict__ uc, const float* __restrict__ Wt,
    float* __restrict__ dbc) {
  __shared__ float As[4][DI];
  int m0 = blockIdx.x * 4;
  int t = threadIdx.x;
  for (int i = t; i < 4 * DI; i += 256) {
    int mm = i >> 9, kk = i & (DI - 1);
    As[mm][kk] = uc[(size_t)(m0 + mm) * DI + kk];
  }
  __syncthreads();
  int n = t & 63, mm = t >> 6;
  if (n < 48) {
    float acc = 0.f;
    for (int k = 0; k < DI; k++) acc = fmaf(As[mm][k], Wt[k * 48 + n], acc);
    dbc[(size_t)(m0 + mm) * 48 + n] = acc;
  }
}

// ---------------------------------------------------------------------------
// Scan pass 1: per (b, chunk, d): chunk transition product P and local state.
// ---------------------------------------------------------------------------
__global__ __launch_bounds__(256) void scan1_kernel(
    const float* __restrict__ delta, const float* __restrict__ uc,
    const float* __restrict__ dbc, const float* __restrict__ a_log_l,
    float* __restrict__ P, float* __restrict__ hloc) {
  int idx = blockIdx.x * 256 + threadIdx.x;  // (b*NCH + c)*DI + d
  int d = idx & (DI - 1);
  int c = (idx >> 9) & (NCH - 1);
  int b = idx >> 15;
  float Aa[DSt];
#pragma unroll
  for (int s = 0; s < DSt; s++) Aa[s] = -__expf(a_log_l[d * DSt + s]);
  float p[DSt], h[DSt];
#pragma unroll
  for (int s = 0; s < DSt; s++) { p[s] = 1.f; h[s] = 0.f; }

  int base_l = b * Ls + c * CLN;
  for (int tt = 0; tt < CLN; tt++) {
    size_t row = (size_t)(base_l + tt);
    float dlt = delta[row * DI + d];
    float uu = uc[row * DI + d];
    float du = dlt * uu;
    const float* Bp = dbc + row * 48 + DRk;
#pragma unroll
    for (int s = 0; s < DSt; s++) {
      float dA = __expf(dlt * Aa[s]);
      p[s] *= dA;
      h[s] = fmaf(dA, h[s], du * Bp[s]);
    }
  }
  size_t o = (size_t)idx * DSt;
#pragma unroll
  for (int s = 0; s < DSt; s++) { P[o + s] = p[s]; hloc[o + s] = h[s]; }
}

// ---------------------------------------------------------------------------
// Scan pass 2: stitch chunk boundary states. Thread per (b, d, s).
// ---------------------------------------------------------------------------
__global__ __launch_bounds__(256) void scan2_kernel(
    const float* __restrict__ P, const float* __restrict__ hloc,
    float* __restrict__ h0) {
  int idx = blockIdx.x * 256 + threadIdx.x;  // b*(DI*DSt) + ds
  int b = idx >> 13;
  int ds = idx & 8191;
  float h = 0.f;
  for (int c = 0; c < NCH; c++) {
    size_t o = ((size_t)(b * NCH + c)) * (DI * DSt) + ds;
    h0[o] = h;
    h = fmaf(P[o], h, hloc[o]);
  }
}

// ---------------------------------------------------------------------------
// Scan pass 3: replay chunk from h0, emit gated g = y*silu(z) as bf16.
// ---------------------------------------------------------------------------
__global__ __launch_bounds__(256) void scan3_kernel(
    const float* __restrict__ delta, const float* __restrict__ uc,
    const float* __restrict__ dbc, const float* __restrict__ a_log_l,
    const float* __restrict__ dparam_l, const float* __restrict__ h0,
    const float* __restrict__ xz, unsigned short* __restrict__ gbf) {
  int idx = blockIdx.x * 256 + threadIdx.x;
  int d = idx & (DI - 1);
  int c = (idx >> 9) & (NCH - 1);
  int b = idx >> 15;
  float Aa[DSt];
#pragma unroll
  for (int s = 0; s < DSt; s++) Aa[s] = -__expf(a_log_l[d * DSt + s]);
  float h[DSt];
  size_t o = (size_t)idx * DSt;
#pragma unroll
  for (int s = 0; s < DSt; s++) h[s] = h0[o + s];
  float Dp = dparam_l[d];

  int base_l = b * Ls + c * CLN;
  for (int tt = 0; tt < CLN; tt++) {
    size_t row = (size_t)(base_l + tt);
    float dlt = delta[row * DI + d];
    float uu = uc[row * DI + d];
    float du = dlt * uu;
    const float* Bp = dbc + row * 48 + DRk;
    const float* Cp = dbc + row * 48 + DRk + DSt;
    float y = 0.f;
#pragma unroll
    for (int s = 0; s < DSt; s++) {
      float dA = __expf(dlt * Aa[s]);
      h[s] = fmaf(dA, h[s], du * Bp[s]);
      y = fmaf(h[s], Cp[s], y);
    }
    y = fmaf(uu, Dp, y);
    float z = xz[row * (2 * DI) + DI + d];
    gbf[row * DI + d] = f2bf(y * silu_f(z));
  }
}

// ---------------------------------------------------------------------------
// LayerNorm over 256 (input already has residual added); writes fp32 + bf16.
// One block (256 thr) per token.
// ---------------------------------------------------------------------------
__global__ __launch_bounds__(256) void ln_kernel(
    const float* __restrict__ yres, const float* __restrict__ lnw_l,
    const float* __restrict__ lnb_l, float* __restrict__ h,
    unsigned short* __restrict__ hb) {
  __shared__ float red[8];
  int m = blockIdx.x, t = threadIdx.x;
  float v = yres[(size_t)m * DM + t];
  float s1 = v, s2 = v * v;
#pragma unroll
  for (int off = 32; off > 0; off >>= 1) {
    s1 += __shfl_down(s1, off, 64);
    s2 += __shfl_down(s2, off, 64);
  }
  if ((t & 63) == 0) { red[t >> 6] = s1; red[4 + (t >> 6)] = s2; }
  __syncthreads();
  float mu  = (red[0] + red[1] + red[2] + red[3]) * (1.f / 256.f);
  float msq = (red[4] + red[5] + red[6] + red[7]) * (1.f / 256.f);
  float inv = rsqrtf(msq - mu * mu + 1e-5f);
  float r = (v - mu) * inv * lnw_l[t] + lnb_l[t];
  h[(size_t)m * DM + t] = r;
  hb[(size_t)m * DM + t] = f2bf(r);
}

// ---------------------------------------------------------------------------
extern "C" void kernel_launch(void* const* d_in, const int* in_sizes, int n_in,
                              void* d_out, int out_size, void* d_ws,
                              size_t ws_size, hipStream_t stream) {
  const float* x      = (const float*)d_in[0];
  const float* ipw    = (const float*)d_in[1];
  const float* ipb    = (const float*)d_in[2];
  const float* opw    = (const float*)d_in[3];
  const float* opb    = (const float*)d_in[4];
  const float* inw    = (const float*)d_in[5];
  const float* convw  = (const float*)d_in[6];
  const float* convb  = (const float*)d_in[7];
  const float* xpw    = (const float*)d_in[8];
  const float* dtw    = (const float*)d_in[9];
  const float* dtb    = (const float*)d_in[10];
  const float* a_log  = (const float*)d_in[11];
  const float* dparam = (const float*)d_in[12];
  const float* outw   = (const float*)d_in[13];
  const float* lnw    = (const float*)d_in[14];
  const float* lnb    = (const float*)d_in[15];
  float* out = (float*)d_out;

  float* ws = (float*)d_ws;
  size_t o = 0;
  float* h    = ws + o; o += (size_t)M * DM;        // fp32 h (single buffer)
  float* xz   = ws + o; o += (size_t)M * 2 * DI;
  float* uc   = ws + o; o += (size_t)M * DI;
  float* dbc  = ws + o; o += (size_t)M * 48;
  float* dlt  = ws + o; o += (size_t)M * DI;
  size_t scan_sz = (size_t)Bb * NCH * DI * DSt;     // 2,097,152
  float* Pb   = ws + o; o += scan_sz;               // aliased: yln (post-scan2)
  float* hlb  = ws + o; o += scan_sz;               // aliased: gbf (post-scan2)
  float* h0b  = ws + o; o += scan_sz;
  float* ipw_t = ws + o; o += (size_t)DIN * DM;
  float* xpw_t = ws + o; o += (size_t)NL * 48 * DI;
  float* dtw_t = ws + o; o += (size_t)NL * DRk * DI;
  unsigned short* hb    = (unsigned short*)(ws + o); o += (size_t)M * DM / 2;
  unsigned short* inwb  = (unsigned short*)(ws + o); o += (size_t)NL * 2 * DI * DM / 2;
  unsigned short* outwb = (unsigned short*)(ws + o); o += (size_t)NL * DM * DI / 2;
  unsigned short* opwb  = (unsigned short*)(ws + o); o += (size_t)DM * DM / 2;
  float* yln = Pb;                     // reuse after scan2 consumed Pb
  unsigned short* gbf = (unsigned short*)hlb;  // reuse after scan2 consumed hlb
  (void)ws_size; (void)in_sizes; (void)n_in; (void)out_size;

  auto T = [&](const float* s, float* dst, int nm, int N, int K) {
    int total = nm * N * K;
    transpose_w<<<dim3((total + 255) / 256), dim3(256), 0, stream>>>(s, dst, nm, N, K);
  };
  T(ipw, ipw_t, 1, DM, DIN);
  T(xpw, xpw_t, NL, 48, DI);
  T(dtw, dtw_t, NL, DI, DRk);
  auto CB = [&](const float* s, unsigned short* dst, int n) {
    cast_bf16<<<dim3((n + 255) / 256), dim3(256), 0, stream>>>(s, dst, n);
  };
  CB(inw, inwb, NL * 2 * DI * DM);
  CB(outw, outwb, NL * DM * DI);
  CB(opw, opwb, DM * DM);

  // input projection: x(8192x64) @ ipw_t + b -> h (fp32) + hb (bf16)
  matmul_tm<DIN, DM, 16, 1, 0><<<dim3(M / 16), dim3(256), 0, stream>>>(
      x, DIN, ipw_t, ipb, h, hb);

  for (int l = 0; l < NL; l++) {
    const unsigned short* inwb_l  = inwb  + (size_t)l * 2 * DI * DM;
    const unsigned short* outwb_l = outwb + (size_t)l * DM * DI;
    const float* xpw_tl  = xpw_t + (size_t)l * 48 * DI;
    const float* dtw_tl  = dtw_t + (size_t)l * DRk * DI;
    const float* a_log_l = a_log + (size_t)l * DI * DSt;

    // xz = h @ inw^T  (8192 x 1024), bf16 MFMA
    gemm_bf16<DM, 2 * DI, 128, 128, 0>
        <<<dim3(M / 128, (2 * DI) / 128), dim3(256), 0, stream>>>(
            hb, inwb_l, nullptr, xz);
    // conv + silu -> uc
    conv_silu_kernel<<<dim3(M * DI / 256), dim3(256), 0, stream>>>(
        xz, convw + (size_t)l * DI * DCv, convb + (size_t)l * DI, uc);
    // dbc = uc @ xpw^T (8192 x 48), fp32
    xpw_matmul_kernel<<<dim3(M / 4), dim3(256), 0, stream>>>(uc, xpw_tl, dbc);
    // delta = softplus(dt @ dtw^T + dtb), fp32 (K=16)
    matmul_tm<DRk, DI, 16, 2, 1><<<dim3(M / 16), dim3(256), 0, stream>>>(
        dbc, 48, dtw_tl, dtb + (size_t)l * DI, dlt, nullptr);
    // chunked selective scan (fp32)
    scan1_kernel<<<dim3(Bb * NCH * DI / 256), dim3(256), 0, stream>>>(
        dlt, uc, dbc, a_log_l, Pb, hlb);
    scan2_kernel<<<dim3(Bb * DI * DSt / 256), dim3(256), 0, stream>>>(Pb, hlb, h0b);
    scan3_kernel<<<dim3(Bb * NCH * DI / 256), dim3(256), 0, stream>>>(
        dlt, uc, dbc, a_log_l, dparam + (size_t)l * DI, h0b, xz, gbf);
    // yln = g @ outw^T + h (residual), bf16 MFMA
    gemm_bf16<DI, DM, 64, 128, 2>
        <<<dim3(M / 64, DM / 128), dim3(256), 0, stream>>>(
            gbf, outwb_l, h, yln);
    // LayerNorm -> h (fp32) + hb (bf16)
    ln_kernel<<<dim3(M), dim3(256), 0, stream>>>(
        yln, lnw + (size_t)l * DM, lnb + (size_t)l * DM, h, hb);
  }

  // final projection: h(8192x256) @ opw^T + b -> out, bf16 MFMA
  gemm_bf16<DM, DM, 64, 128, 1>
      <<<dim3(M / 64, DM / 128), dim3(256), 0, stream>>>(
          hb, opwb, opb, out);
}

// Round 3
// 723.055 us; speedup vs baseline: 1.7550x; 1.2574x over previous
//
#include <hip/hip_runtime.h>
#include <math.h>

// Problem dims
constexpr int Bb  = 4;
constexpr int Ls  = 2048;
constexpr int DM  = 256;   // d_model
constexpr int DI  = 512;   // d_inner
constexpr int DSt = 16;    // d_state
constexpr int DRk = 16;    // dt_rank
constexpr int NL  = 4;
constexpr int DIN = 64;
constexpr int M   = Bb * Ls;   // 8192 tokens

#define NCH 64   // scan chunks
#define CLN 32   // chunk length

using f32x4  = __attribute__((ext_vector_type(4))) float;
using bf16x8 = __attribute__((ext_vector_type(8))) __bf16;

__device__ __forceinline__ float silu_f(float x) { return x / (1.f + __expf(-x)); }
__device__ __forceinline__ float softplus_f(float x) {
  return fmaxf(x, 0.f) + log1pf(__expf(-fabsf(x)));
}
__device__ __forceinline__ unsigned short f2bf(float x) {
  union { float f; unsigned u; } v; v.f = x;
  unsigned r = v.u + 0x7fff + ((v.u >> 16) & 1);
  return (unsigned short)(r >> 16);
}
__device__ __forceinline__ float bf2f(unsigned short v) {
  union { unsigned u; float f; } x; x.u = ((unsigned)v) << 16; return x.f;
}
// async global->LDS 16B/lane; LDS dest = wave-uniform base + lane*16
__device__ __forceinline__ void gl_lds16(const unsigned short* g, unsigned short* l) {
  __builtin_amdgcn_global_load_lds(
      (const __attribute__((address_space(1))) unsigned int*)(const void*)g,
      (__attribute__((address_space(3))) unsigned int*)(void*)l, 16, 0, 0);
}

// ---------------------------------------------------------------------------
// One-shot weight prep: transposes (fp32) + bf16 casts, single kernel.
// ---------------------------------------------------------------------------
__global__ __launch_bounds__(256) void prep_kernel(
    const float* __restrict__ ipw, const float* __restrict__ xpw,
    const float* __restrict__ dtw, const float* __restrict__ inw,
    const float* __restrict__ outw, const float* __restrict__ opw,
    float* __restrict__ ipw_t, float* __restrict__ xpw_t,
    float* __restrict__ dtw_t, unsigned short* __restrict__ inwb,
    unsigned short* __restrict__ outwb, unsigned short* __restrict__ opwb) {
  int i = blockIdx.x * 256 + threadIdx.x;
  const int S0 = 16384, S1 = 98304, S2 = 32768, S3 = 1048576, S4 = 524288, S5 = 65536;
  if (i < S0) { int k = i >> 8, n = i & 255; ipw_t[i] = ipw[n * 64 + k]; return; }
  i -= S0;
  if (i < S1) {
    int l = i / 24576, r = i % 24576, k = r / 48, n = r % 48;
    xpw_t[i] = xpw[l * 24576 + n * 512 + k]; return;
  }
  i -= S1;
  if (i < S2) {
    int l = i >> 13, rr = i & 8191, r = rr >> 9, d = rr & 511;
    dtw_t[i] = dtw[l * 8192 + d * 16 + r]; return;
  }
  i -= S2;
  if (i < S3) { inwb[i] = f2bf(inw[i]); return; }
  i -= S3;
  if (i < S4) { outwb[i] = f2bf(outw[i]); return; }
  i -= S4;
  if (i < S5) { opwb[i] = f2bf(opw[i]); }
}

// ---------------------------------------------------------------------------
// fp32 matmul for in_proj (K=64): C = A[M,K] * Wt[K,N] + bias; + bf16 shadow.
// ---------------------------------------------------------------------------
template <int K, int N, int TM, int PT>
__global__ __launch_bounds__(256) void matmul_tm(
    const float* __restrict__ A, int lda,
    const float* __restrict__ Wt, const float* __restrict__ bias,
    float* __restrict__ C, unsigned short* __restrict__ Cb) {
  __shared__ float As[TM][K];
  const int m0 = blockIdx.x * TM;
  const int t = threadIdx.x;
  for (int i = t; i < TM * K; i += 256) {
    int mm = i / K, kk = i % K;
    As[mm][kk] = A[(size_t)(m0 + mm) * lda + kk];
  }
  __syncthreads();
  float acc[TM][PT];
#pragma unroll
  for (int mm = 0; mm < TM; mm++)
#pragma unroll
    for (int p = 0; p < PT; p++) acc[mm][p] = 0.f;
  for (int k = 0; k < K; k++) {
    float w[PT];
#pragma unroll
    for (int p = 0; p < PT; p++) w[p] = Wt[(size_t)k * N + p * 256 + t];
#pragma unroll
    for (int mm = 0; mm < TM; mm++) {
      float a = As[mm][k];
#pragma unroll
      for (int p = 0; p < PT; p++) acc[mm][p] = fmaf(a, w[p], acc[mm][p]);
    }
  }
#pragma unroll
  for (int mm = 0; mm < TM; mm++) {
#pragma unroll
    for (int p = 0; p < PT; p++) {
      int n = p * 256 + t;
      float v = acc[mm][p] + bias[n];
      C[(size_t)(m0 + mm) * N + n] = v;
      Cb[(size_t)(m0 + mm) * N + n] = f2bf(v);
    }
  }
}

// ---------------------------------------------------------------------------
// bf16 MFMA GEMM, m97-style staging (global_load_lds width 16, LDK=32 unpadded)
// W is [Ntot][K] row-major (= B^T). 4 waves 2x2.
// MODE 1: C[gr*Ntot+gc] = v + extra[gc]  (bias)
// MODE 3: split: gc<DI -> C (fp32, stride DI), else Cb bf16 (stride DI)
// ---------------------------------------------------------------------------
template <int K, int Ntot, int BM, int BN, int MODE>
__global__ __launch_bounds__(256) void gemm_bf16(
    const unsigned short* __restrict__ A,
    const unsigned short* __restrict__ W,
    const float* __restrict__ extra,
    float* __restrict__ C, unsigned short* __restrict__ Cb) {
  constexpr int WM = BM / 2, WN = BN / 2, MI = WM / 16, NI = WN / 16;
  constexpr int CH = (BM + BN) / 16;
  __shared__ __align__(16) unsigned short S[(BM + BN) * 32];
  const int t = threadIdx.x;
  const int m0 = blockIdx.x * BM, n0 = blockIdx.y * BN;
  const int wave = t >> 6, lane = t & 63;
  const int wm = wave & 1, wn = wave >> 1;
  const int lm = lane & 15, quad = lane >> 4;
  const int lrow = lane >> 2, lcol = (lane & 3) * 8;

  f32x4 acc[MI][NI];
#pragma unroll
  for (int i = 0; i < MI; i++)
#pragma unroll
    for (int j = 0; j < NI; j++) acc[i][j] = (f32x4){0.f, 0.f, 0.f, 0.f};

  for (int k0 = 0; k0 < K; k0 += 32) {
    if (k0) __syncthreads();
    for (int c = wave; c < CH; c += 4) {
      int row0 = c * 16;
      const unsigned short* src =
          (row0 < BM) ? A + (size_t)(m0 + row0 + lrow) * K + k0 + lcol
                      : W + (size_t)(n0 + row0 - BM + lrow) * K + k0 + lcol;
      gl_lds16(src, &S[row0 * 32]);
    }
    __syncthreads();
    bf16x8 af[MI], bfr[NI];
#pragma unroll
    for (int i = 0; i < MI; i++)
      af[i] = *(const bf16x8*)&S[(wm * WM + i * 16 + lm) * 32 + quad * 8];
#pragma unroll
    for (int j = 0; j < NI; j++)
      bfr[j] = *(const bf16x8*)&S[(BM + wn * WN + j * 16 + lm) * 32 + quad * 8];
#pragma unroll
    for (int i = 0; i < MI; i++)
#pragma unroll
      for (int j = 0; j < NI; j++)
        acc[i][j] = __builtin_amdgcn_mfma_f32_16x16x32_bf16(
            af[i], bfr[j], acc[i][j], 0, 0, 0);
  }
#pragma unroll
  for (int i = 0; i < MI; i++)
#pragma unroll
    for (int j = 0; j < NI; j++)
#pragma unroll
      for (int r = 0; r < 4; r++) {
        int gr = m0 + wm * WM + i * 16 + quad * 4 + r;
        int gc = n0 + wn * WN + j * 16 + lm;
        float v = acc[i][j][r];
        if constexpr (MODE == 1) {
          C[(size_t)gr * Ntot + gc] = v + extra[gc];
        } else {  // MODE 3
          if (gc < DI) C[(size_t)gr * DI + gc] = v;
          else Cb[(size_t)gr * DI + gc - DI] = f2bf(v);
        }
      }
}

// ---------------------------------------------------------------------------
// outw GEMM (K=512, N=256) + residual + LayerNorm fused. BM=32, BN=256.
// Waves 2x2: WM=16, WN=128, MI=1, NI=8. Block spans full rows -> in-block LN.
// ---------------------------------------------------------------------------
__global__ __launch_bounds__(256) void gemm_outw_ln(
    const unsigned short* __restrict__ A,   // gbf [M][512]
    const unsigned short* __restrict__ W,   // outwb_l [256][512]
    const float* __restrict__ lnw_l, const float* __restrict__ lnb_l,
    float* __restrict__ h, unsigned short* __restrict__ hb) {
  constexpr int BM = 32, BN = 256, K = 512, NI = 8, CH = (BM + BN) / 16;
  __shared__ __align__(16) unsigned short S[(BM + BN) * 32];
  __shared__ float redS[2][2][16], redQ[2][2][16];
  const int t = threadIdx.x;
  const int m0 = blockIdx.x * BM;
  const int wave = t >> 6, lane = t & 63;
  const int wm = wave & 1, wn = wave >> 1;
  const int lm = lane & 15, quad = lane >> 4;
  const int lrow = lane >> 2, lcol = (lane & 3) * 8;

  f32x4 acc[NI];
#pragma unroll
  for (int j = 0; j < NI; j++) acc[j] = (f32x4){0.f, 0.f, 0.f, 0.f};

  for (int k0 = 0; k0 < K; k0 += 32) {
    if (k0) __syncthreads();
    for (int c = wave; c < CH; c += 4) {
      int row0 = c * 16;
      const unsigned short* src =
          (row0 < BM) ? A + (size_t)(m0 + row0 + lrow) * K + k0 + lcol
                      : W + (size_t)(row0 - BM + lrow) * K + k0 + lcol;
      gl_lds16(src, &S[row0 * 32]);
    }
    __syncthreads();
    bf16x8 af = *(const bf16x8*)&S[(wm * 16 + lm) * 32 + quad * 8];
#pragma unroll
    for (int j = 0; j < NI; j++) {
      bf16x8 bfr = *(const bf16x8*)&S[(BM + wn * 128 + j * 16 + lm) * 32 + quad * 8];
      acc[j] = __builtin_amdgcn_mfma_f32_16x16x32_bf16(af, bfr, acc[j], 0, 0, 0);
    }
  }

  // epilogue: v = acc + residual; LN over 256 cols per row
  float vv[NI][4];
#pragma unroll
  for (int j = 0; j < NI; j++)
#pragma unroll
    for (int r = 0; r < 4; r++) {
      int gr = m0 + wm * 16 + quad * 4 + r;
      int gc = wn * 128 + j * 16 + lm;
      vv[j][r] = acc[j][r] + h[(size_t)gr * DM + gc];
    }
  float s1[4], s2[4];
#pragma unroll
  for (int r = 0; r < 4; r++) {
    float a = 0.f, b = 0.f;
#pragma unroll
    for (int j = 0; j < NI; j++) { a += vv[j][r]; b += vv[j][r] * vv[j][r]; }
    s1[r] = a; s2[r] = b;
  }
#pragma unroll
  for (int off = 1; off < 16; off <<= 1) {
#pragma unroll
    for (int r = 0; r < 4; r++) {
      s1[r] += __shfl_xor(s1[r], off, 64);
      s2[r] += __shfl_xor(s2[r], off, 64);
    }
  }
  if (lm == 0) {
#pragma unroll
    for (int r = 0; r < 4; r++) {
      redS[wm][wn][quad * 4 + r] = s1[r];
      redQ[wm][wn][quad * 4 + r] = s2[r];
    }
  }
  __syncthreads();
#pragma unroll
  for (int r = 0; r < 4; r++) {
    int row16 = quad * 4 + r;
    int gr = m0 + wm * 16 + row16;
    float mu  = (redS[wm][0][row16] + redS[wm][1][row16]) * (1.f / 256.f);
    float msq = (redQ[wm][0][row16] + redQ[wm][1][row16]) * (1.f / 256.f);
    float inv = rsqrtf(msq - mu * mu + 1e-5f);
#pragma unroll
    for (int j = 0; j < NI; j++) {
      int gc = wn * 128 + j * 16 + lm;
      float o = (vv[j][r] - mu) * inv * lnw_l[gc] + lnb_l[gc];
      h[(size_t)gr * DM + gc] = o;
      hb[(size_t)gr * DM + gc] = f2bf(o);
    }
  }
}

// ---------------------------------------------------------------------------
// Fused conv(k=4)+SiLU -> uc; dbc = uc @ xpw^T (dt kept in LDS, B/C written);
// delta = softplus(dt @ dtw^T + dtb). Block = 8 tokens.
// ---------------------------------------------------------------------------
__global__ __launch_bounds__(256) void conv_dbc_delta(
    const float* __restrict__ u_g, const float* __restrict__ convw_l,
    const float* __restrict__ convb_l, const float* __restrict__ xpw_tl,
    const float* __restrict__ dtw_tl, const float* __restrict__ dtb_l,
    float* __restrict__ uc, float* __restrict__ dbc32,
    float* __restrict__ dlt) {
  __shared__ float us[11][512];
  __shared__ float ucs[8][512];
  __shared__ float dts[8][16];
  const int m0 = blockIdx.x * 8;
  const int l0 = m0 & (Ls - 1);
  const int t = threadIdx.x;

  for (int i = t; i < 11 * 512; i += 256) {
    int rr = i >> 9, d = i & 511;
    int l = l0 - 3 + rr;
    us[rr][d] = (l >= 0) ? u_g[(size_t)(m0 - 3 + rr) * 512 + d] : 0.f;
  }
  __syncthreads();
  for (int i = t; i < 8 * 512; i += 256) {
    int tt = i >> 9, d = i & 511;
    float a = convb_l[d];
#pragma unroll
    for (int k = 0; k < 4; k++) a = fmaf(us[tt + k][d], convw_l[d * 4 + k], a);
    float v = silu_f(a);
    ucs[tt][d] = v;
    uc[(size_t)(m0 + tt) * 512 + d] = v;
  }
  __syncthreads();
  for (int o = t; o < 8 * 48; o += 256) {
    int tt = o / 48, n = o % 48;
    float a = 0.f;
    for (int k = 0; k < 512; k++) a = fmaf(ucs[tt][k], xpw_tl[k * 48 + n], a);
    if (n < 16) dts[tt][n] = a;
    else dbc32[(size_t)(m0 + tt) * 32 + (n - 16)] = a;
  }
  __syncthreads();
  for (int i = t; i < 8 * 512; i += 256) {
    int tt = i >> 9, d = i & 511;
    float a = dtb_l[d];
#pragma unroll
    for (int r = 0; r < 16; r++) a = fmaf(dts[tt][r], dtw_tl[r * 512 + d], a);
    dlt[(size_t)(m0 + tt) * 512 + d] = softplus_f(a);
  }
}

// ---------------------------------------------------------------------------
// Scan pass 1: per (b, chunk, d): transition product P and local end-state.
// ---------------------------------------------------------------------------
__global__ __launch_bounds__(256) void scan1_kernel(
    const float* __restrict__ delta, const float* __restrict__ uc,
    const float* __restrict__ dbc32, const float* __restrict__ a_log_l,
    float* __restrict__ P, float* __restrict__ hloc) {
  int idx = blockIdx.x * 256 + threadIdx.x;
  int d = idx & (DI - 1);
  int c = (idx >> 9) & (NCH - 1);
  int b = idx >> 15;
  float Aa[DSt];
#pragma unroll
  for (int s = 0; s < DSt; s++) Aa[s] = -__expf(a_log_l[d * DSt + s]);
  float p[DSt], h[DSt];
#pragma unroll
  for (int s = 0; s < DSt; s++) { p[s] = 1.f; h[s] = 0.f; }
  int base_l = b * Ls + c * CLN;
  for (int tt = 0; tt < CLN; tt++) {
    size_t row = (size_t)(base_l + tt);
    float dlt = delta[row * DI + d];
    float uu = uc[row * DI + d];
    float du = dlt * uu;
    const float* Bp = dbc32 + row * 32;
#pragma unroll
    for (int s = 0; s < DSt; s++) {
      float dA = __expf(dlt * Aa[s]);
      p[s] *= dA;
      h[s] = fmaf(dA, h[s], du * Bp[s]);
    }
  }
  size_t o = (size_t)idx * DSt;
#pragma unroll
  for (int s = 0; s < DSt; s++) { P[o + s] = p[s]; hloc[o + s] = h[s]; }
}

// ---------------------------------------------------------------------------
// Scan pass 2: stitch chunk boundary states. 64-thread blocks for spread.
// ---------------------------------------------------------------------------
__global__ __launch_bounds__(64) void scan2_kernel(
    const float* __restrict__ P, const float* __restrict__ hloc,
    float* __restrict__ h0) {
  int idx = blockIdx.x * 64 + threadIdx.x;
  int b = idx >> 13;
  int ds = idx & 8191;
  float h = 0.f;
  for (int c = 0; c < NCH; c++) {
    size_t o = ((size_t)(b * NCH + c)) * (DI * DSt) + ds;
    h0[o] = h;
    h = fmaf(P[o], h, hloc[o]);
  }
}

// ---------------------------------------------------------------------------
// Scan pass 3: replay chunk from h0; g = y*silu(z) written bf16.
// ---------------------------------------------------------------------------
__global__ __launch_bounds__(256) void scan3_kernel(
    const float* __restrict__ delta, const float* __restrict__ uc,
    const float* __restrict__ dbc32, const float* __restrict__ a_log_l,
    const float* __restrict__ dparam_l, const float* __restrict__ h0,
    const unsigned short* __restrict__ zb, unsigned short* __restrict__ gbf) {
  int idx = blockIdx.x * 256 + threadIdx.x;
  int d = idx & (DI - 1);
  int c = (idx >> 9) & (NCH - 1);
  int b = idx >> 15;
  float Aa[DSt];
#pragma unroll
  for (int s = 0; s < DSt; s++) Aa[s] = -__expf(a_log_l[d * DSt + s]);
  float h[DSt];
  size_t o = (size_t)idx * DSt;
#pragma unroll
  for (int s = 0; s < DSt; s++) h[s] = h0[o + s];
  float Dp = dparam_l[d];
  int base_l = b * Ls + c * CLN;
  for (int tt = 0; tt < CLN; tt++) {
    size_t row = (size_t)(base_l + tt);
    float dlt = delta[row * DI + d];
    float uu = uc[row * DI + d];
    float du = dlt * uu;
    const float* Bp = dbc32 + row * 32;
    const float* Cp = dbc32 + row * 32 + 16;
    float y = 0.f;
#pragma unroll
    for (int s = 0; s < DSt; s++) {
      float dA = __expf(dlt * Aa[s]);
      h[s] = fmaf(dA, h[s], du * Bp[s]);
      y = fmaf(h[s], Cp[s], y);
    }
    y = fmaf(uu, Dp, y);
    float z = bf2f(zb[row * DI + d]);
    gbf[row * DI + d] = f2bf(y * silu_f(z));
  }
}

// ---------------------------------------------------------------------------
extern "C" void kernel_launch(void* const* d_in, const int* in_sizes, int n_in,
                              void* d_out, int out_size, void* d_ws,
                              size_t ws_size, hipStream_t stream) {
  const float* x      = (const float*)d_in[0];
  const float* ipw    = (const float*)d_in[1];
  const float* ipb    = (const float*)d_in[2];
  const float* opw    = (const float*)d_in[3];
  const float* opb    = (const float*)d_in[4];
  const float* inw    = (const float*)d_in[5];
  const float* convw  = (const float*)d_in[6];
  const float* convb  = (const float*)d_in[7];
  const float* xpw    = (const float*)d_in[8];
  const float* dtw    = (const float*)d_in[9];
  const float* dtb    = (const float*)d_in[10];
  const float* a_log  = (const float*)d_in[11];
  const float* dparam = (const float*)d_in[12];
  const float* outw   = (const float*)d_in[13];
  const float* lnw    = (const float*)d_in[14];
  const float* lnb    = (const float*)d_in[15];
  float* out = (float*)d_out;

  float* ws = (float*)d_ws;
  size_t o = 0;
  float* h     = ws + o; o += (size_t)M * DM;
  float* u_g   = ws + o; o += (size_t)M * DI;
  float* uc    = ws + o; o += (size_t)M * DI;
  float* dlt   = ws + o; o += (size_t)M * DI;
  float* dbc32 = ws + o; o += (size_t)M * 32;
  size_t scan_sz = (size_t)Bb * NCH * DI * DSt;
  float* Pb  = ws + o; o += scan_sz;
  float* hlb = ws + o; o += scan_sz;
  float* h0b = ws + o; o += scan_sz;
  float* ipw_t = ws + o; o += (size_t)DIN * DM;
  float* xpw_t = ws + o; o += (size_t)NL * DI * 48;
  float* dtw_t = ws + o; o += (size_t)NL * DRk * DI;
  unsigned short* hb    = (unsigned short*)(ws + o); o += (size_t)M * DM / 2;
  unsigned short* zb    = (unsigned short*)(ws + o); o += (size_t)M * DI / 2;
  unsigned short* gbf   = (unsigned short*)(ws + o); o += (size_t)M * DI / 2;
  unsigned short* inwb  = (unsigned short*)(ws + o); o += (size_t)NL * 2 * DI * DM / 2;
  unsigned short* outwb = (unsigned short*)(ws + o); o += (size_t)NL * DM * DI / 2;
  unsigned short* opwb  = (unsigned short*)(ws + o); o += (size_t)DM * DM / 2;
  (void)ws_size; (void)in_sizes; (void)n_in; (void)out_size;

  // weight prep: 1,785,856 elements -> 6976 blocks
  prep_kernel<<<dim3(6976), dim3(256), 0, stream>>>(
      ipw, xpw, dtw, inw, outw, opw, ipw_t, xpw_t, dtw_t, inwb, outwb, opwb);

  // in_proj: x(8192x64) @ ipw_t + b -> h fp32 + hb bf16
  matmul_tm<DIN, DM, 16, 1><<<dim3(M / 16), dim3(256), 0, stream>>>(
      x, DIN, ipw_t, ipb, h, hb);

  for (int l = 0; l < NL; l++) {
    const unsigned short* inwb_l  = inwb  + (size_t)l * 2 * DI * DM;
    const unsigned short* outwb_l = outwb + (size_t)l * DM * DI;
    const float* xpw_tl  = xpw_t + (size_t)l * DI * 48;
    const float* dtw_tl  = dtw_t + (size_t)l * DRk * DI;
    const float* a_log_l = a_log + (size_t)l * DI * DSt;

    // xz = h @ inw^T: u half -> fp32, z half -> bf16
    gemm_bf16<DM, 2 * DI, 128, 128, 3>
        <<<dim3(M / 128, (2 * DI) / 128), dim3(256), 0, stream>>>(
            hb, inwb_l, nullptr, u_g, zb);
    // conv+silu + dbc + delta (fused)
    conv_dbc_delta<<<dim3(M / 8), dim3(256), 0, stream>>>(
        u_g, convw + (size_t)l * DI * 4, convb + (size_t)l * DI,
        xpw_tl, dtw_tl, dtb + (size_t)l * DI, uc, dbc32, dlt);
    // chunked selective scan
    scan1_kernel<<<dim3(Bb * NCH * DI / 256), dim3(256), 0, stream>>>(
        dlt, uc, dbc32, a_log_l, Pb, hlb);
    scan2_kernel<<<dim3(Bb * DI * DSt / 64), dim3(64), 0, stream>>>(Pb, hlb, h0b);
    scan3_kernel<<<dim3(Bb * NCH * DI / 256), dim3(256), 0, stream>>>(
        dlt, uc, dbc32, a_log_l, dparam + (size_t)l * DI, h0b, zb, gbf);
    // outw GEMM + residual + LayerNorm (fused) -> h fp32 + hb bf16
    gemm_outw_ln<<<dim3(M / 32), dim3(256), 0, stream>>>(
        gbf, outwb_l, lnw + (size_t)l * DM, lnb + (size_t)l * DM, h, hb);
  }

  // final projection: hb @ opw^T + b -> out
  gemm_bf16<DM, DM, 64, 128, 1>
      <<<dim3(M / 64, DM / 128), dim3(256), 0, stream>>>(
          hb, opwb, opb, out, nullptr);
}